// Round 3
// baseline (1162.336 us; speedup 1.0000x reference)
//
#include <hip/hip_runtime.h>
#include <hip/hip_cooperative_groups.h>
#include <math.h>

namespace cg = cooperative_groups;

// Problem constants
#define D_FEAT 8192
#define T_RES  2048
#define NC4    2048          // float4 columns
#define LORD   16

// Persistent kernel geometry: 256 blocks x 512 threads, 1 block/CU, 8 rows/block.
#define NTHR   512
#define NBLK   256
#define ROWS   8
#define CPT    4             // float4 per thread (512*4 = 2048 float4 = 8192 floats)

// Workspace layout (float offsets). ~9.1 MB of the 268 MB ws.
#define OFF_Q    0                          // 16 x 8192 Lanczos basis
#define OFF_W    (LORD*D_FEAT)              // unscaled w vector
#define OFF_U    (OFF_W + D_FEAT)           // U[k][t] = (R q_k)_t, 16x2048
#define OFF_PART (OFF_U + LORD*T_RES)       // 256 x 8192 partial y
#define OFF_SCAL (OFF_PART + NBLK*D_FEAT)

#define SC_FF    0
#define SC_FHF   1
#define SC_NF2   2
#define SC_ALPHA 3    // 16
#define SC_BETA2 19   // 16
#define SC_C     35   // 16 steps x 17 slots
#define SC_COEF  307  // 16
#define SCAL_N   352

// Column reduce: block owns 8 float4 cols (bid*8 .. +8). 64 row-groups x 8 cols.
// Returns reduced float4 for lanes tid<8 (col = tid).
__device__ __forceinline__ float4 col_reduce(const float* __restrict__ part,
                                             int bid, int tid, float4* lds4)
{
    const float4* p4 = (const float4*)part;
    const int col = tid & 7, rg = tid >> 3;
    const int c4  = (bid << 3) + col;
    float4 acc = make_float4(0.f, 0.f, 0.f, 0.f);
    #pragma unroll
    for (int i = 0; i < 4; ++i) {
        float4 t = p4[(size_t)(rg*4 + i)*NC4 + c4];
        acc.x += t.x; acc.y += t.y; acc.z += t.z; acc.w += t.w;
    }
    lds4[tid] = acc;
    __syncthreads();
    float4 a2 = make_float4(0.f, 0.f, 0.f, 0.f);
    if (tid < 64) {
        a2 = lds4[tid];
        #pragma unroll
        for (int i = 1; i < 8; ++i) {
            float4 t = lds4[tid + 64*i];
            a2.x += t.x; a2.y += t.y; a2.z += t.z; a2.w += t.w;
        }
        #pragma unroll
        for (int m = 8; m < 64; m <<= 1) {
            a2.x += __shfl_xor(a2.x, m, 64);
            a2.y += __shfl_xor(a2.y, m, 64);
            a2.z += __shfl_xor(a2.z, m, 64);
            a2.w += __shfl_xor(a2.w, m, 64);
        }
    }
    return a2;
}

__global__ __launch_bounds__(NTHR, 2) void k_all(
    const float* __restrict__ Rm, const float* __restrict__ f,
    const float* __restrict__ Dm, float* __restrict__ out,
    float* __restrict__ ws)
{
    cg::grid_group grid = cg::this_grid();
    __shared__ float4 lds4[NTHR];
    __shared__ float  ldsr[64];
    __shared__ float  cs[LORD];

    float* Qb   = ws + OFF_Q;
    float* W    = ws + OFF_W;
    float* U    = ws + OFF_U;
    float* part = ws + OFF_PART;
    float* scal = ws + OFF_SCAL;

    const int tid  = threadIdx.x, bid = blockIdx.x;
    const int wave = tid >> 6,    lane = tid & 63;

    if (bid == 0)
        for (int i = tid; i < SCAL_N; i += NTHR) scal[i] = 0.f;

    // Load this block's 8 R-rows into registers ONCE (held across all 17 steps).
    const float4* R4 = (const float4*)Rm;
    const size_t  t0 = (size_t)bid * ROWS;
    float4 row[ROWS][CPT];   // 128 VGPRs
    #pragma unroll
    for (int r = 0; r < ROWS; ++r)
        #pragma unroll
        for (int c = 0; c < CPT; ++c)
            row[r][c] = R4[(t0 + r)*NC4 + tid + NTHR*c];

    grid.sync();  // scal zeroed + R loads done

    // ===== INIT phase 1: u = R f ; partials of Hf = -R^T u ; f.f ; f.Hf =====
    {
        const float4* v4 = (const float4*)f;
        float4 q[CPT];
        #pragma unroll
        for (int c = 0; c < CPT; ++c) q[c] = v4[tid + NTHR*c];
        if (bid == 0) {
            float ffp = 0.f;
            #pragma unroll
            for (int c = 0; c < CPT; ++c)
                ffp += q[c].x*q[c].x + q[c].y*q[c].y + q[c].z*q[c].z + q[c].w*q[c].w;
            #pragma unroll
            for (int o = 32; o > 0; o >>= 1) ffp += __shfl_down(ffp, o, 64);
            if (lane == 0) atomicAdd(scal + SC_FF, ffp);
        }
        float s[ROWS];
        #pragma unroll
        for (int r = 0; r < ROWS; ++r) {
            float acc = 0.f;
            #pragma unroll
            for (int c = 0; c < CPT; ++c)
                acc += row[r][c].x*q[c].x + row[r][c].y*q[c].y
                     + row[r][c].z*q[c].z + row[r][c].w*q[c].w;
            s[r] = acc;
        }
        #pragma unroll
        for (int o = 32; o > 0; o >>= 1)
            #pragma unroll
            for (int r = 0; r < ROWS; ++r) s[r] += __shfl_down(s[r], o, 64);
        if (lane == 0) {
            #pragma unroll
            for (int r = 0; r < ROWS; ++r) ldsr[r*8 + wave] = s[r];
        }
        __syncthreads();
        float val = ldsr[lane];
        #pragma unroll
        for (int m = 1; m < 8; m <<= 1) val += __shfl_xor(val, m, 64);
        float u[ROWS];
        #pragma unroll
        for (int r = 0; r < ROWS; ++r) u[r] = __shfl(val, r*8, 64);
        float4* p4 = (float4*)part + (size_t)bid*NC4;
        #pragma unroll
        for (int c = 0; c < CPT; ++c) {
            float4 y = make_float4(0.f, 0.f, 0.f, 0.f);
            #pragma unroll
            for (int r = 0; r < ROWS; ++r) {
                y.x -= u[r]*row[r][c].x; y.y -= u[r]*row[r][c].y;
                y.z -= u[r]*row[r][c].z; y.w -= u[r]*row[r][c].w;
            }
            p4[tid + NTHR*c] = y;
        }
        if (tid == 0) {
            float ap = 0.f;
            #pragma unroll
            for (int r = 0; r < ROWS; ++r) ap += u[r]*u[r];
            atomicAdd(scal + SC_FHF, -ap);
        }
    }
    grid.sync();

    // ===== INIT phase 2: F = E f - Hf ; W = F ; nf2 =====
    {
        float4 y = col_reduce(part, bid, tid, lds4);
        if (tid < 8) {
            const int c4 = (bid << 3) + tid;
            const float E = scal[SC_FHF] / (scal[SC_FF] + 1e-15f);
            const float4 fv = ((const float4*)f)[c4];
            float4 F = make_float4(E*fv.x - y.x, E*fv.y - y.y,
                                   E*fv.z - y.z, E*fv.w - y.w);
            float n2 = F.x*F.x + F.y*F.y + F.z*F.z + F.w*F.w;
            n2 += __shfl_down(n2, 4, 64);
            n2 += __shfl_down(n2, 2, 64);
            n2 += __shfl_down(n2, 1, 64);
            if (tid == 0) atomicAdd(scal + SC_NF2, n2);
            ((float4*)W)[c4] = F;
        }
    }
    grid.sync();

    // ===== Lanczos: 16 steps =====
    for (int j = 0; j < LORD; ++j) {
        // phase 1: q = W/||W|| ; u = R q ; partial y = -u^T rows ; a, c_k atomics
        const float b2prev = (j == 0) ? scal[SC_NF2] : scal[SC_BETA2 + (j - 1)];
        const float scale  = rsqrtf(fmaxf(b2prev, 1e-60f));  // ref: w/max(b,1e-30)
        const float4* v4 = (const float4*)W;
        float4 q[CPT];
        #pragma unroll
        for (int c = 0; c < CPT; ++c) {
            float4 t = v4[tid + NTHR*c];
            t.x *= scale; t.y *= scale; t.z *= scale; t.w *= scale;
            q[c] = t;
        }
        if (bid == 0) {   // publish Q[j]
            float4* Q4 = (float4*)(Qb + (size_t)j*D_FEAT);
            #pragma unroll
            for (int c = 0; c < CPT; ++c) Q4[tid + NTHR*c] = q[c];
        }
        float s[ROWS];
        #pragma unroll
        for (int r = 0; r < ROWS; ++r) {
            float acc = 0.f;
            #pragma unroll
            for (int c = 0; c < CPT; ++c)
                acc += row[r][c].x*q[c].x + row[r][c].y*q[c].y
                     + row[r][c].z*q[c].z + row[r][c].w*q[c].w;
            s[r] = acc;
        }
        #pragma unroll
        for (int o = 32; o > 0; o >>= 1)
            #pragma unroll
            for (int r = 0; r < ROWS; ++r) s[r] += __shfl_down(s[r], o, 64);
        if (lane == 0) {
            #pragma unroll
            for (int r = 0; r < ROWS; ++r) ldsr[r*8 + wave] = s[r];
        }
        __syncthreads();
        float val = ldsr[lane];
        #pragma unroll
        for (int m = 1; m < 8; m <<= 1) val += __shfl_xor(val, m, 64);
        if (wave == 0 && (lane & 7) == 0)
            U[(size_t)j*T_RES + t0 + (lane >> 3)] = val;
        float u[ROWS];
        #pragma unroll
        for (int r = 0; r < ROWS; ++r) u[r] = __shfl(val, r*8, 64);
        float4* p4 = (float4*)part + (size_t)bid*NC4;
        #pragma unroll
        for (int c = 0; c < CPT; ++c) {
            float4 y = make_float4(0.f, 0.f, 0.f, 0.f);
            #pragma unroll
            for (int r = 0; r < ROWS; ++r) {
                y.x -= u[r]*row[r][c].x; y.y -= u[r]*row[r][c].y;
                y.z -= u[r]*row[r][c].z; y.w -= u[r]*row[r][c].w;
            }
            p4[tid + NTHR*c] = y;
        }
        if (tid == 0) {
            float ap = 0.f;
            #pragma unroll
            for (int r = 0; r < ROWS; ++r) ap += u[r]*u[r];
            atomicAdd(scal + SC_ALPHA + j, -ap);
            atomicAdd(scal + SC_C + j*17 + j, -ap);   // c_raw_j = a_j
        }
        if (wave == 0 && lane < j) {   // c_raw_k = Q_k.y = -U_k.u
            float cp = 0.f;
            #pragma unroll
            for (int r = 0; r < ROWS; ++r)
                cp += U[(size_t)lane*T_RES + t0 + r] * u[r];
            atomicAdd(scal + SC_C + j*17 + lane, -cp);
        }
        grid.sync();

        if (j == LORD - 1) break;   // beta[15]/w_16 unused by the reference

        // phase 2: w = colsum(part) - sum_{k<=j} c_k Q_k ; beta2[j] = |w|^2
        {
            float4 y = col_reduce(part, bid, tid, lds4);
            if (tid < 8) {
                const int c4 = (bid << 3) + tid;
                const float* cv = scal + SC_C + j*17;
                for (int k = 0; k <= j; ++k) {
                    const float ck = cv[k];
                    const float4 qk = ((const float4*)Qb)[(size_t)k*NC4 + c4];
                    y.x -= ck*qk.x; y.y -= ck*qk.y; y.z -= ck*qk.z; y.w -= ck*qk.w;
                }
                float b2 = y.x*y.x + y.y*y.y + y.z*y.z + y.w*y.w;
                b2 += __shfl_down(b2, 4, 64);
                b2 += __shfl_down(b2, 2, 64);
                b2 += __shfl_down(b2, 1, 64);
                if (tid == 0) atomicAdd(scal + SC_BETA2 + j, b2);
                ((float4*)W)[c4] = y;
            }
        }
        grid.sync();
    }

    // ===== coeffs = normF * exp(-tau*T) e0 (fp64 Taylor, ||tau*T|| <= ~0.6) =====
    if (bid == 0 && wave == 0) {
        double a = 0.0, bl = 0.0;
        if (lane < LORD)     a  = (double)scal[SC_ALPHA + lane];
        if (lane < LORD - 1) bl = sqrt(fmax((double)scal[SC_BETA2 + lane], 0.0));
        double bprev = __shfl_up(bl, 1, 64);
        if (lane == 0) bprev = 0.0;
        if (lane >= LORD) { a = 0.0; bl = 0.0; bprev = 0.0; }
        double v = (lane == 0) ? 1.0 : 0.0;
        double accd = v;
        for (int n = 1; n <= 30; ++n) {
            double vm = __shfl_up(v, 1, 64);   if (lane == 0)        vm = 0.0;
            double vp = __shfl_down(v, 1, 64); if (lane >= LORD - 1) vp = 0.0;
            const double tv = a*v + bprev*vm + bl*vp;
            v = tv * (-0.08 / (double)n);
            accd += v;
        }
        if (lane < LORD) {
            const float nf = sqrtf(fmaxf(scal[SC_NF2], 0.f));
            scal[SC_COEF + lane] = (float)accd * nf;
        }
    }
    grid.sync();

    // ===== final: dtheta[p] = (D[p].dir)/(|D[p]|^2 + 1e-4), dir = sum coef_l Q_l
    if (bid < 16) {
        if (tid < LORD) cs[tid] = scal[SC_COEF + tid];
        __syncthreads();
        const float4* D4 = (const float4*)(Dm + (size_t)bid*D_FEAT);
        const float4* Q4 = (const float4*)Qb;
        float num = 0.f, den = 0.f;
        #pragma unroll
        for (int c = 0; c < CPT; ++c) {
            const int i4 = tid + NTHR*c;
            const float4 dv = D4[i4];
            float4 dir = make_float4(0.f, 0.f, 0.f, 0.f);
            #pragma unroll
            for (int l = 0; l < LORD; ++l) {
                const float cl = cs[l];
                const float4 qv = Q4[(size_t)l*NC4 + i4];
                dir.x += cl*qv.x; dir.y += cl*qv.y; dir.z += cl*qv.z; dir.w += cl*qv.w;
            }
            num += dv.x*dir.x + dv.y*dir.y + dv.z*dir.z + dv.w*dir.w;
            den += dv.x*dv.x + dv.y*dv.y + dv.z*dv.z + dv.w*dv.w;
        }
        #pragma unroll
        for (int o = 32; o > 0; o >>= 1) {
            num += __shfl_down(num, o, 64);
            den += __shfl_down(den, o, 64);
        }
        if (lane == 0) { ldsr[wave] = num; ldsr[8 + wave] = den; }
        __syncthreads();
        if (tid == 0) {
            float n = 0.f, d = 0.f;
            #pragma unroll
            for (int w = 0; w < 8; ++w) { n += ldsr[w]; d += ldsr[8 + w]; }
            out[bid] = n / (d + 1e-4f);
        }
    }
}

extern "C" void kernel_launch(void* const* d_in, const int* in_sizes, int n_in,
                              void* d_out, int out_size, void* d_ws, size_t ws_size,
                              hipStream_t stream)
{
    (void)in_sizes; (void)n_in; (void)out_size; (void)ws_size;
    const float* f  = (const float*)d_in[0];
    const float* Rm = (const float*)d_in[1];
    const float* Dm = (const float*)d_in[2];
    float* outp = (float*)d_out;
    float* ws   = (float*)d_ws;
    void* args[] = { (void*)&Rm, (void*)&f, (void*)&Dm, (void*)&outp, (void*)&ws };
    hipLaunchCooperativeKernel((const void*)k_all, dim3(NBLK), dim3(NTHR),
                               args, 0, stream);
}